// Round 8
// baseline (151.741 us; speedup 1.0000x reference)
//
#include <hip/hip_runtime.h>
#include <hip/hip_bf16.h>

// Reference semantics (n=512, HIDDEN=128, GRID=32, POOL=8, N_CELLS=4):
//   ped j bins into a 32x32 subcell grid centred on ped i; last-write-wins
//   in ascending-j order == max-j wins; out-of-range j writes a ZERO vector
//   to cell 0 (can overwrite an in-range winner) -> winner enc 2j+1 / 2j,
//   LDS atomicMax, parity selects contribution. pooled k = h*16 + g;
//   out = relu(pooled @ W + b).  ALL TENSORS FP32.
// History: r3 100.6; r4 T-factorization REGRESSED (+15); r5 99.2 (winner
// compaction); r6 98.0 (split-K=16); r7 97.7 (16 rows/block). ~82us of
// dur_us is two harness 256MiB ws-poison fills in the timed window.
// r8 change: fuse finish into gemm via last-block-done reduction (per-ig
// atomic counter, zeroed by pool; release fence by ALL threads before the
// bump, acquire fence by the winner — cross-XCD part visibility, G16).
// Removes one dispatch + its graph gap; tail = one 256KB reduction/ig.

#define N_PED 512
#define HID   128
#define KDIM  2048   // HID * 16
#define OUTD  128
#define NSLOT 32     // 16 k-chunks x 2 halves
#define NIG   32     // i-groups of 16 rows

// ---------------- Kernel A: winner table + compact + pooled features ------
__global__ __launch_bounds__(256) void pool_kernel(
    const float* __restrict__ hidden,   // (512,128)
    const float* __restrict__ obs2,     // (512,2)
    float*       __restrict__ pooled,   // (512,2048) k = h*16 + g
    int*         __restrict__ cnt)      // (32,) per-ig arrival counters
{
    __shared__ int winner[1024];
    __shared__ int glist[16 * 64];      // per-coarse-cell winner j lists
    __shared__ int gcnt[16];

    const int i   = blockIdx.x;
    const int tid = threadIdx.x;

    // zero the gemm arrival counters (ws is poisoned 0xAA every launch);
    // stream order guarantees visibility before gemm_part runs.
    if (i < NIG && tid == 0) cnt[i] = 0;

    for (int c = tid; c < 1024; c += 256) winner[c] = -1;
    if (tid < 16) gcnt[tid] = 0;
    const float2 pi = ((const float2*)obs2)[i];
    __syncthreads();

    // Phase 1: scatter winners (2 j's per thread).
    for (int j = tid; j < N_PED; j += 256) {
        if (j == i) continue;
        const float2 pj = ((const float2*)obs2)[j];
        const float ox = (pj.x - pi.x) * 4.0f + 16.0f;  // /0.25 == *4 exact
        const float oy = (pj.y - pi.y) * 4.0f + 16.0f;
        const bool in = (ox >= 0.f) && (ox < 32.f) && (oy >= 0.f) && (oy < 32.f);
        int c, enc;
        if (in) { c = ((int)ox) * 32 + (int)oy; enc = 2 * j + 1; }
        else    { c = 0;                        enc = 2 * j;     }
        atomicMax(&winner[c], enc);
    }
    __syncthreads();

    // Phase 2a: compact in-range winners per coarse cell.
    // NB: w=-1 has (w&1)==1 -> must test w>0. cell c = cx*32+cy;
    // coarse g = (cx>>3)*4 + (cy>>3) = ((c>>8)&3)*4 + ((c>>3)&3).
    #pragma unroll
    for (int r = 0; r < 4; ++r) {
        const int c = r * 256 + tid;
        const int w = winner[c];
        if (w > 0 && (w & 1)) {
            const int g   = ((c >> 8) & 3) * 4 + ((c >> 3) & 3);
            const int pos = atomicAdd(&gcnt[g], 1);
            glist[g * 64 + pos] = w >> 1;
        }
    }
    __syncthreads();

    // Phase 2b: gather. group g = tid>>4, lane = tid&15 covers 8 channels;
    // 16 lanes span one hidden row (512B, 32B/lane). ~19 iters avg.
    const int g    = tid >> 4;
    const int lane = tid & 15;
    const int h0   = lane * 8;
    const int n    = gcnt[g];

    float acc[8] = {0.f,0.f,0.f,0.f,0.f,0.f,0.f,0.f};
    for (int e = 0; e < n; ++e) {
        const int j = glist[g * 64 + e];     // broadcast within group
        const float4 r0 = *(const float4*)(hidden + j * HID + h0);
        const float4 r1 = *(const float4*)(hidden + j * HID + h0 + 4);
        acc[0] += r0.x; acc[1] += r0.y; acc[2] += r0.z; acc[3] += r0.w;
        acc[4] += r1.x; acc[5] += r1.y; acc[6] += r1.z; acc[7] += r1.w;
    }

    float* dst = pooled + i * KDIM;
    #pragma unroll
    for (int q = 0; q < 8; ++q)
        dst[(h0 + q) * 16 + g] = acc[q];
}

// ------- Kernel B: split-K GEMM partials + fused last-block epilogue ------
// grid (32 i-groups of 16, 16 k-chunks of 128); 256 thr: o = tid&127,
// half = tid>>7 covers 64 k. part[i][slot][o], 32 slots. The 16th block
// of an ig to arrive reduces part + bias + relu -> out.
__global__ __launch_bounds__(256) void gemm_part(
    const float* __restrict__ pooled,  // (512,2048)
    const float* __restrict__ W,       // (2048,128)
    float*       __restrict__ part,    // (512,32,128)
    const float* __restrict__ bias,    // (128,)
    float*       __restrict__ out,     // (512,128)
    int*         __restrict__ cnt)     // (32,)
{
    const int ig   = blockIdx.x;      // 0..31
    const int kc   = blockIdx.y;      // 0..15
    const int tid  = threadIdx.x;
    const int o    = tid & 127;
    const int half = tid >> 7;
    const int kbase = kc * 128 + half * 64;

    const float* pb = pooled + ig * 16 * KDIM + kbase;

    float acc[16];
    #pragma unroll
    for (int r = 0; r < 16; ++r) acc[r] = 0.f;

    for (int kk = 0; kk < 64; kk += 4) {
        const int kb = (kbase + kk) * OUTD + o;
        const float w0 = W[kb];
        const float w1 = W[kb + OUTD];
        const float w2 = W[kb + 2 * OUTD];
        const float w3 = W[kb + 3 * OUTD];
        #pragma unroll
        for (int r = 0; r < 16; ++r) {
            const float4 a = *(const float4*)(pb + r * KDIM + kk);
            acc[r] += a.x * w0 + a.y * w1 + a.z * w2 + a.w * w3;
        }
    }
    const int slot = kc * 2 + half;
    #pragma unroll
    for (int r = 0; r < 16; ++r)
        part[((ig * 16 + r) * NSLOT + slot) * OUTD + o] = acc[r];

    // ---- fused epilogue: last-arriving block of this ig reduces ----
    __threadfence();                 // each thread publishes ITS stores
    __syncthreads();                 // all fences done before the bump
    __shared__ int amlast;
    if (tid == 0) amlast = (atomicAdd(&cnt[ig], 1) == 15);
    __syncthreads();
    if (amlast) {
        __threadfence();             // acquire: drop stale lines
        const float bv = bias[o];
        #pragma unroll
        for (int r = 0; r < 8; ++r) {
            const int row = ig * 16 + half * 8 + r;
            const float* pp = part + (row * NSLOT) * OUTD + o;
            float s = bv;
            #pragma unroll
            for (int m = 0; m < NSLOT; ++m)
                s += pp[m * OUTD];
            out[row * OUTD + o] = fmaxf(s, 0.f);
        }
    }
}

extern "C" void kernel_launch(void* const* d_in, const int* in_sizes, int n_in,
                              void* d_out, int out_size, void* d_ws, size_t ws_size,
                              hipStream_t stream) {
    (void)in_sizes; (void)n_in; (void)out_size; (void)ws_size;
    const float* hidden = (const float*)d_in[0];  // (512,128)
    // d_in[1] = obs1, unused for type_='social'
    const float* obs2   = (const float*)d_in[2];  // (512,2)
    const float* W      = (const float*)d_in[3];  // (2048,128)
    const float* bias   = (const float*)d_in[4];  // (128,)

    float* pooled = (float*)d_ws;                    // 512*2048 f32 = 4 MB
    float* part   = pooled + (size_t)N_PED * KDIM;   // 512*32*128 f32 = 8 MB
    int*   cnt    = (int*)(part + (size_t)N_PED * NSLOT * OUTD);  // 32 ints

    pool_kernel<<<dim3(N_PED), dim3(256), 0, stream>>>(hidden, obs2, pooled, cnt);
    gemm_part<<<dim3(32, 16), dim3(256), 0, stream>>>(pooled, W, part, bias,
                                                      (float*)d_out, cnt);
}

// Round 9
// 97.628 us; speedup vs baseline: 1.5543x; 1.5543x over previous
//
#include <hip/hip_runtime.h>
#include <hip/hip_bf16.h>

// Reference semantics (n=512, HIDDEN=128, GRID=32, POOL=8, N_CELLS=4):
//   ped j bins into a 32x32 subcell grid centred on ped i; last-write-wins
//   in ascending-j order == max-j wins; out-of-range j writes a ZERO vector
//   to cell 0 (can overwrite an in-range winner) -> winner enc 2j+1 / 2j,
//   LDS atomicMax, parity selects contribution. pooled k = h*16 + g;
//   out = relu(pooled @ W + b).  ALL TENSORS FP32.
// History: r3 100.6; r4 T-factorization REGRESSED (+15, occupancy/cross-XCD);
// r5 99.2 (winner compaction); r6 98.0 (split-K=16); r7 97.7 (16 rows/blk);
// r8 single-kernel fused epilogue REGRESSED (+54us: per-block device-scope
// __threadfence on non-coherent L2s = serialized L2 writebacks; gemm 79us).
// LESSON: producer->consumer across blocks must stay a kernel boundary.
// ~81us of dur_us is two harness 256MiB ws-poison fills in the timed window;
// controllable budget ~16us (kernels ~6us + graph/restore gaps ~10us).
// r9: revert to r7 + float4-vectorized finish (bitwise-same sum order).

#define N_PED 512
#define HID   128
#define KDIM  2048   // HID * 16
#define OUTD  128
#define NSLOT 32     // 16 k-chunks x 2 halves

// ---------------- Kernel A: winner table + compact + pooled features ------
__global__ __launch_bounds__(256) void pool_kernel(
    const float* __restrict__ hidden,   // (512,128)
    const float* __restrict__ obs2,     // (512,2)
    float*       __restrict__ pooled)   // (512,2048) k = h*16 + g
{
    __shared__ int winner[1024];
    __shared__ int glist[16 * 64];      // per-coarse-cell winner j lists
    __shared__ int gcnt[16];

    const int i   = blockIdx.x;
    const int tid = threadIdx.x;

    for (int c = tid; c < 1024; c += 256) winner[c] = -1;
    if (tid < 16) gcnt[tid] = 0;
    const float2 pi = ((const float2*)obs2)[i];
    __syncthreads();

    // Phase 1: scatter winners (2 j's per thread).
    for (int j = tid; j < N_PED; j += 256) {
        if (j == i) continue;
        const float2 pj = ((const float2*)obs2)[j];
        const float ox = (pj.x - pi.x) * 4.0f + 16.0f;  // /0.25 == *4 exact
        const float oy = (pj.y - pi.y) * 4.0f + 16.0f;
        const bool in = (ox >= 0.f) && (ox < 32.f) && (oy >= 0.f) && (oy < 32.f);
        int c, enc;
        if (in) { c = ((int)ox) * 32 + (int)oy; enc = 2 * j + 1; }
        else    { c = 0;                        enc = 2 * j;     }
        atomicMax(&winner[c], enc);
    }
    __syncthreads();

    // Phase 2a: compact in-range winners per coarse cell.
    // NB: w=-1 has (w&1)==1 -> must test w>0. cell c = cx*32+cy;
    // coarse g = (cx>>3)*4 + (cy>>3) = ((c>>8)&3)*4 + ((c>>3)&3).
    #pragma unroll
    for (int r = 0; r < 4; ++r) {
        const int c = r * 256 + tid;
        const int w = winner[c];
        if (w > 0 && (w & 1)) {
            const int g   = ((c >> 8) & 3) * 4 + ((c >> 3) & 3);
            const int pos = atomicAdd(&gcnt[g], 1);
            glist[g * 64 + pos] = w >> 1;
        }
    }
    __syncthreads();

    // Phase 2b: gather. group g = tid>>4, lane = tid&15 covers 8 channels;
    // 16 lanes span one hidden row (512B, 32B/lane). ~19 iters avg.
    const int g    = tid >> 4;
    const int lane = tid & 15;
    const int h0   = lane * 8;
    const int n    = gcnt[g];

    float acc[8] = {0.f,0.f,0.f,0.f,0.f,0.f,0.f,0.f};
    for (int e = 0; e < n; ++e) {
        const int j = glist[g * 64 + e];     // broadcast within group
        const float4 r0 = *(const float4*)(hidden + j * HID + h0);
        const float4 r1 = *(const float4*)(hidden + j * HID + h0 + 4);
        acc[0] += r0.x; acc[1] += r0.y; acc[2] += r0.z; acc[3] += r0.w;
        acc[4] += r1.x; acc[5] += r1.y; acc[6] += r1.z; acc[7] += r1.w;
    }

    float* dst = pooled + i * KDIM;
    #pragma unroll
    for (int q = 0; q < 8; ++q)
        dst[(h0 + q) * 16 + g] = acc[q];
}

// ---------------- Kernel B: split-K GEMM partials, 16 rows/block ---------
// grid (32 i-groups of 16, 16 k-chunks of 128); 256 thr: o = tid&127,
// half = tid>>7 covers 64 k. part[i][kc*2+half][o], 32 slots.
__global__ __launch_bounds__(256) void gemm_part(
    const float* __restrict__ pooled,  // (512,2048)
    const float* __restrict__ W,       // (2048,128)
    float*       __restrict__ part)    // (512,32,128)
{
    const int ig   = blockIdx.x;      // 0..31
    const int kc   = blockIdx.y;      // 0..15
    const int tid  = threadIdx.x;
    const int o    = tid & 127;
    const int half = tid >> 7;
    const int kbase = kc * 128 + half * 64;

    const float* pb = pooled + ig * 16 * KDIM + kbase;

    float acc[16];
    #pragma unroll
    for (int r = 0; r < 16; ++r) acc[r] = 0.f;

    for (int kk = 0; kk < 64; kk += 4) {
        const int kb = (kbase + kk) * OUTD + o;
        const float w0 = W[kb];
        const float w1 = W[kb + OUTD];
        const float w2 = W[kb + 2 * OUTD];
        const float w3 = W[kb + 3 * OUTD];
        #pragma unroll
        for (int r = 0; r < 16; ++r) {
            const float4 a = *(const float4*)(pb + r * KDIM + kk);
            acc[r] += a.x * w0 + a.y * w1 + a.z * w2 + a.w * w3;
        }
    }
    const int slot = kc * 2 + half;
    #pragma unroll
    for (int r = 0; r < 16; ++r)
        part[((ig * 16 + r) * NSLOT + slot) * OUTD + o] = acc[r];
}

// ---------------- Kernel C: reduce partials + bias + relu (float4) -------
// 64 blocks x 256 thr; each thread owns 4 consecutive outputs.
__global__ __launch_bounds__(256) void finish_kernel(
    const float* __restrict__ part,   // (512,32,128)
    const float* __restrict__ bias,   // (128,)
    float*       __restrict__ out)    // (512,128)
{
    const int idx = blockIdx.x * 256 + threadIdx.x;  // 0..16383 float4 slots
    const int i  = idx >> 5;          // ped
    const int og = idx & 31;          // float4 group within the row
    const float* pp = part + (i * NSLOT) * OUTD + og * 4;
    float4 s = *(const float4*)(bias + og * 4);
    #pragma unroll
    for (int m = 0; m < NSLOT; ++m) {
        const float4 v = *(const float4*)(pp + m * OUTD);
        s.x += v.x; s.y += v.y; s.z += v.z; s.w += v.w;
    }
    s.x = fmaxf(s.x, 0.f); s.y = fmaxf(s.y, 0.f);
    s.z = fmaxf(s.z, 0.f); s.w = fmaxf(s.w, 0.f);
    *(float4*)(out + i * OUTD + og * 4) = s;
}

extern "C" void kernel_launch(void* const* d_in, const int* in_sizes, int n_in,
                              void* d_out, int out_size, void* d_ws, size_t ws_size,
                              hipStream_t stream) {
    (void)in_sizes; (void)n_in; (void)out_size; (void)ws_size;
    const float* hidden = (const float*)d_in[0];  // (512,128)
    // d_in[1] = obs1, unused for type_='social'
    const float* obs2   = (const float*)d_in[2];  // (512,2)
    const float* W      = (const float*)d_in[3];  // (2048,128)
    const float* bias   = (const float*)d_in[4];  // (128,)

    float* pooled = (float*)d_ws;                    // 512*2048 f32 = 4 MB
    float* part   = pooled + (size_t)N_PED * KDIM;   // 512*32*128 f32 = 8 MB

    pool_kernel<<<dim3(N_PED), dim3(256), 0, stream>>>(hidden, obs2, pooled);
    gemm_part<<<dim3(32, 16), dim3(256), 0, stream>>>(pooled, W, part);
    finish_kernel<<<dim3(64), dim3(256), 0, stream>>>(part, bias, (float*)d_out);
}